// Round 1
// 309.529 us; speedup vs baseline: 1.0083x; 1.0083x over previous
//
#include <hip/hip_runtime.h>
#include <hip/hip_bf16.h>
#include <math.h>

// Problem: B=4, T=2048, C=1024, H=16, D=64, d_half=32
// Dataflow:
//   cast x, w_attn, w_proj -> bf16
//   qkvb = xb @ wab^T  rope+rmsnorm fused into q/k epilogue; v written
//          PRE-TRANSPOSED to vt[b*C + h*64 + d][t] (packed short4 over r)
//   attn (bf16 MFMA flash, fixed-max softmax, fold-paired q-tiles):
//          K staged from qkvb, V^T staged vectorized from vt,
//          kf/vf fragments hoisted & shared across the q-tile pair,
//          Ps XOR-swizzled; y written into qkvb's dead v-columns
//   out  = (qkvb v-cols as y, lda=3072) @ wpb^T  (fp32 out)

#define TT 2048
#define CC 1024
#define HH 16
#define DD 64

typedef __attribute__((ext_vector_type(8))) short short8;
typedef __attribute__((ext_vector_type(4))) short short4_t;
typedef __attribute__((ext_vector_type(4))) float f32x4;
typedef unsigned short ushort_t;

// fp32 -> bf16 (RNE, finite inputs only)
__device__ __forceinline__ ushort_t f2bf(float f) {
    unsigned u = __builtin_bit_cast(unsigned, f);
    u = (u + 0x7fffu + ((u >> 16) & 1u)) >> 16;
    return (ushort_t)u;
}

// ---------------------------------------------------------------------------
// float -> bf16 cast, 8 elements/thread
// ---------------------------------------------------------------------------
__global__ __launch_bounds__(256) void cast_bf16(const float* __restrict__ in,
                                                 ushort_t* __restrict__ out, int n8) {
    const int i = blockIdx.x * 256 + threadIdx.x;
    if (i >= n8) return;
    const float4* p = (const float4*)in + (size_t)i * 2;
    float4 f0 = p[0], f1 = p[1];
    short8 v;
    v[0] = (short)f2bf(f0.x); v[1] = (short)f2bf(f0.y);
    v[2] = (short)f2bf(f0.z); v[3] = (short)f2bf(f0.w);
    v[4] = (short)f2bf(f1.x); v[5] = (short)f2bf(f1.y);
    v[6] = (short)f2bf(f1.z); v[7] = (short)f2bf(f1.w);
    *(short8*)(out + (size_t)i * 8) = v;
}

// ---------------------------------------------------------------------------
// bf16 MFMA GEMM (m97 structure): C = A[M,K](lda) * B[N,K]^T, 128x128 tile.
// ---------------------------------------------------------------------------
template <bool OUTF32>
__global__ __launch_bounds__(256) void gemm_bt(const ushort_t* __restrict__ A,
                                               const ushort_t* __restrict__ B,
                                               void* __restrict__ C,
                                               int M, int N, int K, int lda) {
    __shared__ ushort_t As[128 * 32];
    __shared__ ushort_t Bs[128 * 32];

    const int tid  = threadIdx.x;
    const int wv   = tid >> 6;
    const int ln   = tid & 63;
    const int quad = ln >> 4;
    const int lm   = ln & 15;
    const int wm   = wv & 1;
    const int wn   = wv >> 1;
    const int rowC = blockIdx.y * 128;
    const int colC = blockIdx.x * 128;

    const int srow = wv * 16 + (ln >> 2);
    const int skq  = (ln & 3) * 8;

    f32x4 acc[4][4];
#pragma unroll
    for (int i = 0; i < 4; ++i)
#pragma unroll
        for (int j = 0; j < 4; ++j) acc[i][j] = (f32x4){0.f, 0.f, 0.f, 0.f};

    for (int k0 = 0; k0 < K; k0 += 32) {
        __syncthreads();
#pragma unroll
        for (int half = 0; half < 2; ++half) {
            const ushort_t* gA = A + (size_t)(rowC + half * 64 + srow) * lda + k0 + skq;
            const ushort_t* gB = B + (size_t)(colC + half * 64 + srow) * K + k0 + skq;
            ushort_t* lA = As + (half * 64 + wv * 16) * 32;
            ushort_t* lB = Bs + (half * 64 + wv * 16) * 32;
            __builtin_amdgcn_global_load_lds(
                (const __attribute__((address_space(1))) unsigned int*)gA,
                (__attribute__((address_space(3))) unsigned int*)lA, 16, 0, 0);
            __builtin_amdgcn_global_load_lds(
                (const __attribute__((address_space(1))) unsigned int*)gB,
                (__attribute__((address_space(3))) unsigned int*)lB, 16, 0, 0);
        }
        __syncthreads();

        short8 af[4], bf[4];
#pragma unroll
        for (int mt = 0; mt < 4; ++mt)
            af[mt] = *(const short8*)&As[(wm * 64 + mt * 16 + lm) * 32 + quad * 8];
#pragma unroll
        for (int nt = 0; nt < 4; ++nt)
            bf[nt] = *(const short8*)&Bs[(wn * 64 + nt * 16 + lm) * 32 + quad * 8];
#pragma unroll
        for (int mt = 0; mt < 4; ++mt)
#pragma unroll
            for (int nt = 0; nt < 4; ++nt)
                acc[mt][nt] = __builtin_amdgcn_mfma_f32_16x16x32_bf16(
                    af[mt], bf[nt], acc[mt][nt], 0, 0, 0);
    }

#pragma unroll
    for (int mt = 0; mt < 4; ++mt)
#pragma unroll
        for (int r = 0; r < 4; ++r) {
            const size_t row = rowC + wm * 64 + mt * 16 + quad * 4 + r;
#pragma unroll
            for (int nt = 0; nt < 4; ++nt) {
                const size_t col = colC + wn * 64 + nt * 16 + lm;
                if (OUTF32) ((float*)C)[row * N + col] = acc[mt][nt][r];
                else        ((ushort_t*)C)[row * N + col] = f2bf(acc[mt][nt][r]);
            }
        }
}

// ---------------------------------------------------------------------------
// GEMM1 with fused rope+rmsnorm epilogue on q/k. v-section written
// TRANSPOSED to vtb[(b*CC + h*64 + d)][t] as packed short4 (r = 4 consec t).
// ---------------------------------------------------------------------------
__global__ __launch_bounds__(256) void gemm_qkv(const ushort_t* __restrict__ A,
                                                const ushort_t* __restrict__ B,
                                                ushort_t* __restrict__ C,
                                                ushort_t* __restrict__ vtb,
                                                const float* __restrict__ cosb,
                                                const float* __restrict__ sinb,
                                                int M, int N, int K) {
    __shared__ ushort_t As[128 * 32];
    __shared__ ushort_t Bs[128 * 32];

    const int tid  = threadIdx.x;
    const int wv   = tid >> 6;
    const int ln   = tid & 63;
    const int quad = ln >> 4;
    const int lm   = ln & 15;
    const int wm   = wv & 1;
    const int wn   = wv >> 1;
    const int rowC = blockIdx.y * 128;
    const int colC = blockIdx.x * 128;

    const int srow = wv * 16 + (ln >> 2);
    const int skq  = (ln & 3) * 8;

    f32x4 acc[4][4];
#pragma unroll
    for (int i = 0; i < 4; ++i)
#pragma unroll
        for (int j = 0; j < 4; ++j) acc[i][j] = (f32x4){0.f, 0.f, 0.f, 0.f};

    for (int k0 = 0; k0 < K; k0 += 32) {
        __syncthreads();
#pragma unroll
        for (int half = 0; half < 2; ++half) {
            const ushort_t* gA = A + (size_t)(rowC + half * 64 + srow) * K + k0 + skq;
            const ushort_t* gB = B + (size_t)(colC + half * 64 + srow) * K + k0 + skq;
            ushort_t* lA = As + (half * 64 + wv * 16) * 32;
            ushort_t* lB = Bs + (half * 64 + wv * 16) * 32;
            __builtin_amdgcn_global_load_lds(
                (const __attribute__((address_space(1))) unsigned int*)gA,
                (__attribute__((address_space(3))) unsigned int*)lA, 16, 0, 0);
            __builtin_amdgcn_global_load_lds(
                (const __attribute__((address_space(1))) unsigned int*)gB,
                (__attribute__((address_space(3))) unsigned int*)lB, 16, 0, 0);
        }
        __syncthreads();

        short8 af[4], bf[4];
#pragma unroll
        for (int mt = 0; mt < 4; ++mt)
            af[mt] = *(const short8*)&As[(wm * 64 + mt * 16 + lm) * 32 + quad * 8];
#pragma unroll
        for (int nt = 0; nt < 4; ++nt)
            bf[nt] = *(const short8*)&Bs[(wn * 64 + nt * 16 + lm) * 32 + quad * 8];
#pragma unroll
        for (int mt = 0; mt < 4; ++mt)
#pragma unroll
            for (int nt = 0; nt < 4; ++nt)
                acc[mt][nt] = __builtin_amdgcn_mfma_f32_16x16x32_bf16(
                    af[mt], bf[nt], acc[mt][nt], 0, 0, 0);
    }

    const bool isqk = colC < 2 * CC;   // q or k section
    if (isqk) {
#pragma unroll
        for (int mt = 0; mt < 4; ++mt)
#pragma unroll
            for (int r = 0; r < 4; ++r) {
                const int row = rowC + wm * 64 + mt * 16 + quad * 4 + r;
                ushort_t* Cp = C + (size_t)row * N + colC + wn * 64 + lm;
                const int t = row & (TT - 1);
                float ss = 0.f;
#pragma unroll
                for (int nt = 0; nt < 4; ++nt) ss += acc[mt][nt][r] * acc[mt][nt][r];
                ss += __shfl_xor(ss, 1);
                ss += __shfl_xor(ss, 2);
                ss += __shfl_xor(ss, 4);
                ss += __shfl_xor(ss, 8);
                const float rinv = rsqrtf(ss * (1.0f / 64.0f) + 1e-6f);
                const float c0 = cosb[t * 32 + lm];
                const float c1 = cosb[t * 32 + 16 + lm];
                const float s0 = sinb[t * 32 + lm];
                const float s1 = sinb[t * 32 + 16 + lm];
                const float o0 = acc[mt][0][r] * c0 + acc[mt][2][r] * s0;
                const float o1 = acc[mt][1][r] * c1 + acc[mt][3][r] * s1;
                const float o2 = acc[mt][2][r] * c0 - acc[mt][0][r] * s0;
                const float o3 = acc[mt][3][r] * c1 - acc[mt][1][r] * s1;
                Cp[0]  = f2bf(o0 * rinv);
                Cp[16] = f2bf(o1 * rinv);
                Cp[32] = f2bf(o2 * rinv);
                Cp[48] = f2bf(o3 * rinv);
            }
    } else {
        // v: write transposed. Lane's 4 r-values are 4 consecutive t at one
        // (h,d) row -> one packed 8B store each nt.
#pragma unroll
        for (int mt = 0; mt < 4; ++mt) {
            const int row0 = rowC + wm * 64 + mt * 16 + quad * 4;
            const int bb = row0 >> 11;         // batch
            const int tt = row0 & (TT - 1);    // t of r=0
#pragma unroll
            for (int nt = 0; nt < 4; ++nt) {
                const int hd = colC - 2 * CC + wn * 64 + nt * 16 + lm;
                short4_t pk;
                pk[0] = (short)f2bf(acc[mt][nt][0]);
                pk[1] = (short)f2bf(acc[mt][nt][1]);
                pk[2] = (short)f2bf(acc[mt][nt][2]);
                pk[3] = (short)f2bf(acc[mt][nt][3]);
                *(short4_t*)(vtb + (size_t)(bb * CC + hd) * TT + tt) = pk;
            }
        }
    }
}

// ---------------------------------------------------------------------------
// bf16 MFMA flash attention, fixed-max softmax, fold-paired q-tiles.
// V^T staged vectorized from pre-transposed vt; kf/vf hoisted and shared
// across the q-tile pair; Ps XOR-swizzled (n' = (n>>3 ^ m>>2)<<3 | n&7).
// y written into qkv's dead v-columns (disjoint from K/Q reads).
// ---------------------------------------------------------------------------
__global__ __launch_bounds__(256, 3) void attn_mfma(ushort_t* __restrict__ qkv,
                                                    const ushort_t* __restrict__ vt) {
    const int qp = blockIdx.x;   // 0..15
    const int h  = blockIdx.y;   // 0..15
    const int b  = blockIdx.z;   // 0..3
    const int tid  = threadIdx.x;
    const int w    = tid >> 6;
    const int lane = tid & 63;
    const int quad = lane >> 4;
    const int lm   = lane & 15;
    const int qtA = qp, qtB = 31 - qp;

    __shared__ ushort_t Ks[64][72];    // K[n][d]
    __shared__ ushort_t Vt[64][72];    // V^T[d][n]
    __shared__ ushort_t Ps[4][16][72]; // per-wave P[m][n'], n' block-swizzled

    short8 qfA[2], qfB[2];
    {
        const ushort_t* qa = qkv + (size_t)(b * TT + qtA * 64 + w * 16 + lm) * (3 * CC) + h * DD;
        const ushort_t* qb = qkv + (size_t)(b * TT + qtB * 64 + w * 16 + lm) * (3 * CC) + h * DD;
        qfA[0] = *(const short8*)(qa + quad * 8);
        qfA[1] = *(const short8*)(qa + 32 + quad * 8);
        qfB[0] = *(const short8*)(qb + quad * 8);
        qfB[1] = *(const short8*)(qb + 32 + quad * 8);
    }

    f32x4 OA[4], OB[4];
#pragma unroll
    for (int dt = 0; dt < 4; ++dt) {
        OA[dt] = (f32x4){0.f, 0.f, 0.f, 0.f};
        OB[dt] = (f32x4){0.f, 0.f, 0.f, 0.f};
    }
    float psA[4] = {0.f, 0.f, 0.f, 0.f};
    float psB[4] = {0.f, 0.f, 0.f, 0.f};

    const int sn = tid >> 2;          // staging row (K n-row / V d-row)
    const int sd = (tid & 3) * 16;    // staging col base

    auto process = [&](const short8 (&qf)[2], const short8 (&kf)[2][4],
                       const short8 (&vf)[2][4], f32x4 (&O)[4], float (&ps)[4],
                       bool diag) {
        f32x4 sf[4];
#pragma unroll
        for (int nt = 0; nt < 4; ++nt) sf[nt] = (f32x4){0.f, 0.f, 0.f, 0.f};
#pragma unroll
        for (int kk = 0; kk < 2; ++kk)
#pragma unroll
            for (int nt = 0; nt < 4; ++nt)
                sf[nt] = __builtin_amdgcn_mfma_f32_16x16x32_bf16(qf[kk], kf[kk][nt],
                                                                 sf[nt], 0, 0, 0);
        // p = exp(s*0.125 - 8); scores provably in [-8,8] after rmsnorm.
#pragma unroll
        for (int r = 0; r < 4; ++r) {
            const int rloc = w * 16 + quad * 4 + r;   // row within q-tile
            const int m = quad * 4 + r;
#pragma unroll
            for (int nt = 0; nt < 4; ++nt) {
                const int n = nt * 16 + lm;
                float s = sf[nt][r] * 0.125f - 8.f;
                if (diag) s = (n <= rloc) ? s : -1e30f;
                const float p = __expf(s);
                ps[r] += p;
                Ps[w][m][(((n >> 3) ^ (m >> 2)) << 3) | (n & 7)] = f2bf(p);
            }
        }
#pragma unroll
        for (int kk = 0; kk < 2; ++kk) {
            const short8 pf =
                *(const short8*)&Ps[w][lm][(((kk * 4 + quad) ^ (lm >> 2)) << 3)];
#pragma unroll
            for (int dt = 0; dt < 4; ++dt)
                O[dt] = __builtin_amdgcn_mfma_f32_16x16x32_bf16(pf, vf[kk][dt],
                                                                O[dt], 0, 0, 0);
        }
    };

    for (int kt = 0; kt <= qtB; ++kt) {
        __syncthreads();
        {
            const ushort_t* kp = qkv + (size_t)(b * TT + kt * 64 + sn) * (3 * CC) + CC + h * DD + sd;
            *(short8*)&Ks[sn][sd]     = *(const short8*)kp;
            *(short8*)&Ks[sn][sd + 8] = *(const short8*)(kp + 8);
            const ushort_t* vp = vt + (size_t)(b * CC + h * DD + sn) * TT + kt * 64 + sd;
            *(short8*)&Vt[sn][sd]     = *(const short8*)vp;
            *(short8*)&Vt[sn][sd + 8] = *(const short8*)(vp + 8);
        }
        __syncthreads();

        // hoisted fragments, shared by both fold-paired q-tiles
        short8 kf[2][4], vf[2][4];
#pragma unroll
        for (int kk = 0; kk < 2; ++kk)
#pragma unroll
            for (int i = 0; i < 4; ++i) {
                kf[kk][i] = *(const short8*)&Ks[i * 16 + lm][kk * 32 + quad * 8];
                vf[kk][i] = *(const short8*)&Vt[i * 16 + lm][kk * 32 + quad * 8];
            }

        if (kt <= qtA) process(qfA, kf, vf, OA, psA, kt == qtA);
        process(qfB, kf, vf, OB, psB, kt == qtB);
    }

    // epilogue: reduce row sums once, scale, store into qkv's v-columns
    auto epi = [&](f32x4 (&O)[4], float (&ps)[4], int qt) {
#pragma unroll
        for (int r = 0; r < 4; ++r) {
            float l = ps[r];
            l += __shfl_xor(l, 1);
            l += __shfl_xor(l, 2);
            l += __shfl_xor(l, 4);
            l += __shfl_xor(l, 8);
            const float inv_l = 1.f / l;
            ushort_t* yp = qkv + (size_t)(b * TT + qt * 64 + w * 16 + quad * 4 + r) * (3 * CC)
                               + 2 * CC + h * DD + lm;
#pragma unroll
            for (int dt = 0; dt < 4; ++dt) yp[dt * 16] = f2bf(O[dt][r] * inv_l);
        }
    };
    epi(OA, psA, qtA);
    epi(OB, psB, qtB);
}

// ---------------------------------------------------------------------------
extern "C" void kernel_launch(void* const* d_in, const int* in_sizes, int n_in,
                              void* d_out, int out_size, void* d_ws, size_t ws_size,
                              hipStream_t stream) {
    const float* x      = (const float*)d_in[0];   // (4,2048,1024)
    const float* cosb   = (const float*)d_in[1];   // (1,2048,1,32)
    const float* sinb   = (const float*)d_in[2];
    const float* w_attn = (const float*)d_in[3];   // (3072,1024)
    const float* w_proj = (const float*)d_in[4];   // (1024,1024)
    float* out = (float*)d_out;                    // (4,2048,1024)

    // workspace layout (bf16 elements)
    ushort_t* qkvb = (ushort_t*)d_ws;                       // 8192*3072 (q,k; v-cols hold y)
    ushort_t* vtb  = qkvb + (size_t)8192 * 3072;            // 4096*2048 = 8192*1024 (V^T)
    ushort_t* xb   = vtb  + (size_t)8192 * 1024;            // 8192*1024
    ushort_t* wab  = xb   + (size_t)8192 * 1024;            // 3072*1024
    ushort_t* wpb  = wab  + (size_t)3072 * 1024;            // 1024*1024

    cast_bf16<<<(8192 * 1024 / 8 + 255) / 256, 256, 0, stream>>>(x, xb, 8192 * 1024 / 8);
    cast_bf16<<<(3072 * 1024 / 8 + 255) / 256, 256, 0, stream>>>(w_attn, wab, 3072 * 1024 / 8);
    cast_bf16<<<(1024 * 1024 / 8 + 255) / 256, 256, 0, stream>>>(w_proj, wpb, 1024 * 1024 / 8);

    // qkv = x @ w_attn^T; rope+rmsnorm on q,k; v transposed into vtb
    gemm_qkv<<<dim3(3072 / 128, 8192 / 128), 256, 0, stream>>>(
        xb, wab, qkvb, vtb, cosb, sinb, 8192, 3072, 1024);

    // causal attention -> y into qkvb's v-columns
    attn_mfma<<<dim3(16, HH, 4), 256, 0, stream>>>(qkvb, vtb);

    // out = y @ w_proj^T (fp32 out), A = qkvb v-columns with lda=3072
    gemm_bt<true><<<dim3(1024 / 128, 8192 / 128), 256, 0, stream>>>(
        qkvb + 2 * CC, wpb, out, 8192, 1024, 1024, 3 * CC);
}